// Round 1
// baseline (5449.906 us; speedup 1.0000x reference)
//
#include <hip/hip_runtime.h>

#define BLK 256

static inline int cdiv(int a, int b) { return (a + b - 1) / b; }

// ---------------- feature encoder: x[i,0:8] ----------------
__global__ void k_feat(const int* __restrict__ feat,
                       const float* __restrict__ emb_user,
                       const float* __restrict__ emb_known,
                       const float* __restrict__ w_user,
                       const float* __restrict__ b_user,
                       const float* __restrict__ emb_cat,
                       const float* __restrict__ w_cat,
                       const float* __restrict__ b_cat,
                       float* __restrict__ x,
                       int n, int user_max, int cat_max) {
    int i = blockIdx.x * blockDim.x + threadIdx.x;
    if (i >= n) return;
    int col0 = feat[i * 3 + 0];
    int col1 = feat[i * 3 + 1];
    int typ  = feat[i * 3 + 2];
    float out[8];
    if (typ == 0) {
        int u = min(max(col0, 0), user_max);
        int k = min(max(col1, 0), 1);
        float in[8];
#pragma unroll
        for (int d = 0; d < 8; ++d) {
            float v = emb_user[u * 8 + d] + emb_known[k * 8 + d];
            in[d] = v > 0.f ? v : 0.f;
        }
#pragma unroll
        for (int c = 0; c < 8; ++c) {
            float s = b_user[c];
#pragma unroll
            for (int d = 0; d < 8; ++d) s += in[d] * w_user[d * 8 + c];
            out[c] = s;
        }
    } else {
        int ci = min(max(col0, 0), cat_max);
        float in[4];
#pragma unroll
        for (int d = 0; d < 4; ++d) {
            float v = emb_cat[ci * 4 + d];
            in[d] = v > 0.f ? v : 0.f;
        }
#pragma unroll
        for (int c = 0; c < 8; ++c) {
            float s = b_cat[c];
#pragma unroll
            for (int d = 0; d < 4; ++d) s += in[d] * w_cat[d * 8 + c];
            out[c] = s;
        }
    }
#pragma unroll
    for (int c = 0; c < 8; ++c) x[i * 8 + c] = out[c];
}

// ---------------- degree via atomics ----------------
__global__ void k_deg(const int* __restrict__ dst, float* __restrict__ deg, int e) {
    int i = blockIdx.x * blockDim.x + threadIdx.x;
    if (i < e) atomicAdd(&deg[dst[i]], 1.0f);
}

__global__ void k_rsqrt(float* __restrict__ dinv, int n) {
    int i = blockIdx.x * blockDim.x + threadIdx.x;
    if (i < n) dinv[i] = rsqrtf(dinv[i] + 1.0f);
}

// ---------------- dense matvec: H[n,16] = X[n,CIN] @ W[CIN,16] ----------------
template <int CIN>
__global__ void k_mm(const float* __restrict__ X, const float* __restrict__ W,
                     float* __restrict__ H, int n) {
    __shared__ float ws_[CIN * 16];
    for (int t = threadIdx.x; t < CIN * 16; t += blockDim.x) ws_[t] = W[t];
    __syncthreads();
    int i = blockIdx.x * blockDim.x + threadIdx.x;
    if (i >= n) return;
    float in[CIN];
#pragma unroll
    for (int d = 0; d < CIN; ++d) in[d] = X[(size_t)i * CIN + d];
    float4 o[4];
#pragma unroll
    for (int q = 0; q < 4; ++q) {
        float s[4] = {0.f, 0.f, 0.f, 0.f};
#pragma unroll
        for (int d = 0; d < CIN; ++d) {
#pragma unroll
            for (int j = 0; j < 4; ++j) s[j] += in[d] * ws_[d * 16 + q * 4 + j];
        }
        o[q] = make_float4(s[0], s[1], s[2], s[3]);
    }
    float4* hp = reinterpret_cast<float4*>(H + (size_t)i * 16);
#pragma unroll
    for (int q = 0; q < 4; ++q) hp[q] = o[q];
}

// ---------------- edge scatter: agg[dst] += h[src] * dinv[src]*dinv[dst] ----------------
__global__ void k_scatter(const int* __restrict__ src, const int* __restrict__ dst,
                          const float* __restrict__ dinv, const float* __restrict__ H,
                          float* __restrict__ agg, int e) {
    int i = blockIdx.x * blockDim.x + threadIdx.x;
    if (i >= e) return;
    int s = src[i];
    int d = dst[i];
    float en = dinv[s] * dinv[d];
    const float4* hp = reinterpret_cast<const float4*>(H + (size_t)s * 16);
    float* ap = agg + (size_t)d * 16;
#pragma unroll
    for (int q = 0; q < 4; ++q) {
        float4 v = hp[q];
        atomicAdd(ap + q * 4 + 0, v.x * en);
        atomicAdd(ap + q * 4 + 1, v.y * en);
        atomicAdd(ap + q * 4 + 2, v.z * en);
        atomicAdd(ap + q * 4 + 3, v.w * en);
    }
}

// ---------------- finalize: agg = relu(agg + h*self_norm + b), in place ----------------
__global__ void k_finalize(float* __restrict__ agg, const float* __restrict__ H,
                           const float* __restrict__ dinv, const float* __restrict__ b,
                           int n) {
    int gid = blockIdx.x * blockDim.x + threadIdx.x;
    int i = gid >> 2;
    int q = gid & 3;
    if (i >= n) return;
    float dv = dinv[i];
    float sn = dv * dv;
    float4 a  = reinterpret_cast<float4*>(agg)[(size_t)i * 4 + q];
    float4 h  = reinterpret_cast<const float4*>(H)[(size_t)i * 4 + q];
    float4 bb = reinterpret_cast<const float4*>(b)[q];
    a.x = fmaxf(a.x + h.x * sn + bb.x, 0.f);
    a.y = fmaxf(a.y + h.y * sn + bb.y, 0.f);
    a.z = fmaxf(a.z + h.z * sn + bb.z, 0.f);
    a.w = fmaxf(a.w + h.w * sn + bb.w, 0.f);
    reinterpret_cast<float4*>(agg)[(size_t)i * 4 + q] = a;
}

// ---------------- output heads ----------------
__global__ void k_heads(const float* __restrict__ H,
                        const float* __restrict__ w_mem, const float* __restrict__ b_mem,
                        const float* __restrict__ w_node, const float* __restrict__ b_node,
                        float* __restrict__ out, int n) {
    int i = blockIdx.x * blockDim.x + threadIdx.x;
    if (i >= n) return;
    float h[16];
#pragma unroll
    for (int c = 0; c < 16; ++c) h[c] = H[(size_t)i * 16 + c];
    float m = b_mem[0];
    float n0 = b_node[0];
    float n1 = b_node[1];
#pragma unroll
    for (int c = 0; c < 16; ++c) {
        m  += h[c] * w_mem[c];
        n0 += h[c] * w_node[c * 2 + 0];
        n1 += h[c] * w_node[c * 2 + 1];
    }
    out[i] = m;
    out[n + 2 * i + 0] = n0;
    out[n + 2 * i + 1] = n1;
}

extern "C" void kernel_launch(void* const* d_in, const int* in_sizes, int n_in,
                              void* d_out, int out_size, void* d_ws, size_t ws_size,
                              hipStream_t stream) {
    const int*   edges     = (const int*)d_in[0];
    const int*   feat      = (const int*)d_in[1];
    const float* emb_user  = (const float*)d_in[2];
    const float* emb_known = (const float*)d_in[3];
    const float* w_user    = (const float*)d_in[4];
    const float* b_user    = (const float*)d_in[5];
    const float* emb_cat   = (const float*)d_in[6];
    const float* w_cat     = (const float*)d_in[7];
    const float* b_cat     = (const float*)d_in[8];
    const float* w0        = (const float*)d_in[9];
    const float* b0        = (const float*)d_in[10];
    const float* w2        = (const float*)d_in[11];
    const float* b2        = (const float*)d_in[12];
    const float* w_node    = (const float*)d_in[13];
    const float* b_node    = (const float*)d_in[14];
    const float* w_mem     = (const float*)d_in[15];
    const float* b_mem     = (const float*)d_in[16];

    const int E = in_sizes[0] / 2;
    const int n = in_sizes[1] / 3;
    const int user_max = in_sizes[2] / 8 - 1;  // USER_SIZE-1
    const int cat_max  = in_sizes[6] / 4 - 1;  // CAT_SIZE-1

    const int* src = edges;
    const int* dst = edges + E;

    float* ws   = (float*)d_ws;
    float* x    = ws;                       // n*8
    float* hbuf = x + (size_t)n * 8;        // n*16
    float* agg  = hbuf + (size_t)n * 16;    // n*16
    float* dinv = agg + (size_t)n * 16;     // n

    float* outp = (float*)d_out;

    // degree -> dinv
    hipMemsetAsync(dinv, 0, (size_t)n * sizeof(float), stream);
    k_feat<<<cdiv(n, BLK), BLK, 0, stream>>>(feat, emb_user, emb_known, w_user, b_user,
                                             emb_cat, w_cat, b_cat, x, n, user_max, cat_max);
    k_deg<<<cdiv(E, BLK), BLK, 0, stream>>>(dst, dinv, E);
    k_rsqrt<<<cdiv(n, BLK), BLK, 0, stream>>>(dinv, n);

    // conv 1: x(n,8) -> h1(n,16) in agg
    k_mm<8><<<cdiv(n, BLK), BLK, 0, stream>>>(x, w0, hbuf, n);
    hipMemsetAsync(agg, 0, (size_t)n * 16 * sizeof(float), stream);
    k_scatter<<<cdiv(E, BLK), BLK, 0, stream>>>(src, dst, dinv, hbuf, agg, E);
    k_finalize<<<cdiv(4 * n, BLK), BLK, 0, stream>>>(agg, hbuf, dinv, b0, n);

    // conv 2: h1(n,16) -> h2(n,16) in agg
    k_mm<16><<<cdiv(n, BLK), BLK, 0, stream>>>(agg, w2, hbuf, n);
    hipMemsetAsync(agg, 0, (size_t)n * 16 * sizeof(float), stream);
    k_scatter<<<cdiv(E, BLK), BLK, 0, stream>>>(src, dst, dinv, hbuf, agg, E);
    k_finalize<<<cdiv(4 * n, BLK), BLK, 0, stream>>>(agg, hbuf, dinv, b2, n);

    // heads
    k_heads<<<cdiv(n, BLK), BLK, 0, stream>>>(agg, w_mem, b_mem, w_node, b_node, outp, n);
}

// Round 2
// 535.055 us; speedup vs baseline: 10.1857x; 10.1857x over previous
//
#include <hip/hip_runtime.h>

#define BLK 256

static inline int cdiv(int a, int b) { return (a + b - 1) / b; }

// ---------------- feature encoder: x[i,0:8] ----------------
__global__ void k_feat(const int* __restrict__ feat,
                       const float* __restrict__ emb_user,
                       const float* __restrict__ emb_known,
                       const float* __restrict__ w_user,
                       const float* __restrict__ b_user,
                       const float* __restrict__ emb_cat,
                       const float* __restrict__ w_cat,
                       const float* __restrict__ b_cat,
                       float* __restrict__ x,
                       int n, int user_max, int cat_max) {
    int i = blockIdx.x * blockDim.x + threadIdx.x;
    if (i >= n) return;
    int col0 = feat[i * 3 + 0];
    int col1 = feat[i * 3 + 1];
    int typ  = feat[i * 3 + 2];
    float out[8];
    if (typ == 0) {
        int u = min(max(col0, 0), user_max);
        int k = min(max(col1, 0), 1);
        float in[8];
#pragma unroll
        for (int d = 0; d < 8; ++d) {
            float v = emb_user[u * 8 + d] + emb_known[k * 8 + d];
            in[d] = v > 0.f ? v : 0.f;
        }
#pragma unroll
        for (int c = 0; c < 8; ++c) {
            float s = b_user[c];
#pragma unroll
            for (int d = 0; d < 8; ++d) s += in[d] * w_user[d * 8 + c];
            out[c] = s;
        }
    } else {
        int ci = min(max(col0, 0), cat_max);
        float in[4];
#pragma unroll
        for (int d = 0; d < 4; ++d) {
            float v = emb_cat[ci * 4 + d];
            in[d] = v > 0.f ? v : 0.f;
        }
#pragma unroll
        for (int c = 0; c < 8; ++c) {
            float s = b_cat[c];
#pragma unroll
            for (int d = 0; d < 4; ++d) s += in[d] * w_cat[d * 8 + c];
            out[c] = s;
        }
    }
#pragma unroll
    for (int c = 0; c < 8; ++c) x[i * 8 + c] = out[c];
}

// ---------------- in-degree (int atomics) ----------------
__global__ void k_deg(const int* __restrict__ dst, int* __restrict__ deg, int e) {
    int i = blockIdx.x * blockDim.x + threadIdx.x;
    if (i < e) atomicAdd(&deg[dst[i]], 1);
}

// ---------------- 3-kernel exclusive scan over deg[0..n) ----------------
__global__ void k_scan_block(const int* __restrict__ deg, int* __restrict__ offs,
                             int* __restrict__ bsum, int n) {
    __shared__ int s[BLK];
    int i = blockIdx.x * BLK + threadIdx.x;
    int v = (i < n) ? deg[i] : 0;
    s[threadIdx.x] = v;
    __syncthreads();
    for (int off = 1; off < BLK; off <<= 1) {
        int t = (threadIdx.x >= off) ? s[threadIdx.x - off] : 0;
        __syncthreads();
        s[threadIdx.x] += t;
        __syncthreads();
    }
    if (i < n) offs[i] = s[threadIdx.x] - v;        // exclusive within block
    if (threadIdx.x == BLK - 1) bsum[blockIdx.x] = s[BLK - 1];
}

__global__ void k_scan_top(int* __restrict__ bsum, int nb) {
    __shared__ int s[512];
    int v = (threadIdx.x < nb) ? bsum[threadIdx.x] : 0;
    s[threadIdx.x] = v;
    __syncthreads();
    for (int off = 1; off < 512; off <<= 1) {
        int t = (threadIdx.x >= off) ? s[threadIdx.x - off] : 0;
        __syncthreads();
        s[threadIdx.x] += t;
        __syncthreads();
    }
    if (threadIdx.x < nb) bsum[threadIdx.x] = s[threadIdx.x] - v;   // exclusive
}

__global__ void k_scan_add(int* __restrict__ offs, int* __restrict__ cursor,
                           const int* __restrict__ bsum, int n, int e) {
    int i = blockIdx.x * BLK + threadIdx.x;
    if (i < n) {
        int o = offs[i] + bsum[blockIdx.x];
        offs[i] = o;
        cursor[i] = o;
    }
    if (blockIdx.x == 0 && threadIdx.x == 0) offs[n] = e;
}

// ---------------- dinv = rsqrt(deg+1) ----------------
__global__ void k_dinv(const int* __restrict__ deg, float* __restrict__ dinv, int n) {
    int i = blockIdx.x * blockDim.x + threadIdx.x;
    if (i < n) dinv[i] = rsqrtf((float)deg[i] + 1.0f);
}

// ---------------- CSR fill: group srcs by dst ----------------
__global__ void k_fill(const int* __restrict__ src, const int* __restrict__ dst,
                       int* __restrict__ cursor, int* __restrict__ csr, int e) {
    int i = blockIdx.x * blockDim.x + threadIdx.x;
    if (i >= e) return;
    int d = dst[i];
    int pos = atomicAdd(&cursor[d], 1);
    csr[pos] = src[i];
}

// ---------------- H_s[n,16] = (X[n,CIN] @ W[CIN,16]) * dinv[i] ----------------
template <int CIN>
__global__ void k_mm(const float* __restrict__ X, const float* __restrict__ W,
                     const float* __restrict__ dinv, float* __restrict__ H, int n) {
    __shared__ float ws_[CIN * 16];
    for (int t = threadIdx.x; t < CIN * 16; t += blockDim.x) ws_[t] = W[t];
    __syncthreads();
    int i = blockIdx.x * blockDim.x + threadIdx.x;
    if (i >= n) return;
    float in[CIN];
#pragma unroll
    for (int d = 0; d < CIN; ++d) in[d] = X[(size_t)i * CIN + d];
    float dv = dinv[i];
    float4* hp = reinterpret_cast<float4*>(H + (size_t)i * 16);
#pragma unroll
    for (int q = 0; q < 4; ++q) {
        float s[4] = {0.f, 0.f, 0.f, 0.f};
#pragma unroll
        for (int d = 0; d < CIN; ++d) {
#pragma unroll
            for (int j = 0; j < 4; ++j) s[j] += in[d] * ws_[d * 16 + q * 4 + j];
        }
        hp[q] = make_float4(s[0] * dv, s[1] * dv, s[2] * dv, s[3] * dv);
    }
}

// ---------------- pull + finalize: out = relu(dinv[d]*(sum_{src} Hs[src] + Hs[d]) + b)
// 4 lanes per node, lane q owns channels [4q, 4q+4)
__global__ void k_pull(const int* __restrict__ offs, const int* __restrict__ csr,
                       const float* __restrict__ Hs, const float* __restrict__ dinv,
                       const float* __restrict__ b, float* __restrict__ out, int n) {
    int gid = blockIdx.x * blockDim.x + threadIdx.x;
    int node = gid >> 2;
    int q = gid & 3;
    if (node >= n) return;
    int beg = offs[node];
    int end = offs[node + 1];
    float4 acc = reinterpret_cast<const float4*>(Hs + (size_t)node * 16)[q];  // self term
    for (int e = beg; e < end; ++e) {
        int s = csr[e];
        float4 v = reinterpret_cast<const float4*>(Hs + (size_t)s * 16)[q];
        acc.x += v.x; acc.y += v.y; acc.z += v.z; acc.w += v.w;
    }
    float dv = dinv[node];
    float4 bb = reinterpret_cast<const float4*>(b)[q];
    float4 r;
    r.x = fmaxf(acc.x * dv + bb.x, 0.f);
    r.y = fmaxf(acc.y * dv + bb.y, 0.f);
    r.z = fmaxf(acc.z * dv + bb.z, 0.f);
    r.w = fmaxf(acc.w * dv + bb.w, 0.f);
    reinterpret_cast<float4*>(out + (size_t)node * 16)[q] = r;
}

// ---------------- output heads ----------------
__global__ void k_heads(const float* __restrict__ H,
                        const float* __restrict__ w_mem, const float* __restrict__ b_mem,
                        const float* __restrict__ w_node, const float* __restrict__ b_node,
                        float* __restrict__ out, int n) {
    int i = blockIdx.x * blockDim.x + threadIdx.x;
    if (i >= n) return;
    float h[16];
#pragma unroll
    for (int c = 0; c < 16; ++c) h[c] = H[(size_t)i * 16 + c];
    float m  = b_mem[0];
    float n0 = b_node[0];
    float n1 = b_node[1];
#pragma unroll
    for (int c = 0; c < 16; ++c) {
        m  += h[c] * w_mem[c];
        n0 += h[c] * w_node[c * 2 + 0];
        n1 += h[c] * w_node[c * 2 + 1];
    }
    out[i] = m;
    out[n + 2 * i + 0] = n0;
    out[n + 2 * i + 1] = n1;
}

extern "C" void kernel_launch(void* const* d_in, const int* in_sizes, int n_in,
                              void* d_out, int out_size, void* d_ws, size_t ws_size,
                              hipStream_t stream) {
    const int*   edges     = (const int*)d_in[0];
    const int*   feat      = (const int*)d_in[1];
    const float* emb_user  = (const float*)d_in[2];
    const float* emb_known = (const float*)d_in[3];
    const float* w_user    = (const float*)d_in[4];
    const float* b_user    = (const float*)d_in[5];
    const float* emb_cat   = (const float*)d_in[6];
    const float* w_cat     = (const float*)d_in[7];
    const float* b_cat     = (const float*)d_in[8];
    const float* w0        = (const float*)d_in[9];
    const float* b0        = (const float*)d_in[10];
    const float* w2        = (const float*)d_in[11];
    const float* b2        = (const float*)d_in[12];
    const float* w_node    = (const float*)d_in[13];
    const float* b_node    = (const float*)d_in[14];
    const float* w_mem     = (const float*)d_in[15];
    const float* b_mem     = (const float*)d_in[16];

    const int E = in_sizes[0] / 2;
    const int n = in_sizes[1] / 3;
    const int user_max = in_sizes[2] / 8 - 1;
    const int cat_max  = in_sizes[6] / 4 - 1;
    const int nb = cdiv(n, BLK);

    const int* src = edges;
    const int* dst = edges + E;

    // workspace layout
    float* x    = (float*)d_ws;             // 8n
    float* hs   = x + (size_t)n * 8;        // 16n  (scaled h)
    float* h1   = hs + (size_t)n * 16;      // 16n  (conv outputs; reused for conv2)
    float* dinv = h1 + (size_t)n * 16;      // n
    int* deg    = (int*)(dinv + n);         // n
    int* offs   = deg + n;                  // n+1
    int* cursor = offs + n + 1;             // n
    int* bsum   = cursor + n;               // 512
    int* csr    = bsum + 512;               // E

    float* outp = (float*)d_out;

    // --- graph prep ---
    hipMemsetAsync(deg, 0, (size_t)n * sizeof(int), stream);
    k_feat<<<cdiv(n, BLK), BLK, 0, stream>>>(feat, emb_user, emb_known, w_user, b_user,
                                             emb_cat, w_cat, b_cat, x, n, user_max, cat_max);
    k_deg<<<cdiv(E, BLK), BLK, 0, stream>>>(dst, deg, E);
    k_scan_block<<<nb, BLK, 0, stream>>>(deg, offs, bsum, n);
    k_scan_top<<<1, 512, 0, stream>>>(bsum, nb);
    k_scan_add<<<nb, BLK, 0, stream>>>(offs, cursor, bsum, n, E);
    k_dinv<<<cdiv(n, BLK), BLK, 0, stream>>>(deg, dinv, n);
    k_fill<<<cdiv(E, BLK), BLK, 0, stream>>>(src, dst, cursor, csr, E);

    // --- conv 1: x(n,8) -> h1(n,16) ---
    k_mm<8><<<cdiv(n, BLK), BLK, 0, stream>>>(x, w0, dinv, hs, n);
    k_pull<<<cdiv(4 * n, BLK), BLK, 0, stream>>>(offs, csr, hs, dinv, b0, h1, n);

    // --- conv 2: h1(n,16) -> h2(n,16) (overwrites h1) ---
    k_mm<16><<<cdiv(n, BLK), BLK, 0, stream>>>(h1, w2, dinv, hs, n);
    k_pull<<<cdiv(4 * n, BLK), BLK, 0, stream>>>(offs, csr, hs, dinv, b2, h1, n);

    // --- heads ---
    k_heads<<<cdiv(n, BLK), BLK, 0, stream>>>(h1, w_mem, b_mem, w_node, b_node, outp, n);
}